// Round 9
// baseline (371.714 us; speedup 1.0000x reference)
//
#include <hip/hip_runtime.h>
#include <hip/hip_bf16.h>

// Problem constants
#define Bsz 4
#define Lseq 1024
#define OBS 60
#define DM 256
#define DI 512
#define DTR 16
#define DST 16
#define NTOK (Bsz*Lseq)   // 4096
#define NCH 64            // scan chunks per sequence
#define CH  16            // steps per chunk

typedef _Float16 half8 __attribute__((ext_vector_type(8)));
typedef float floatx4 __attribute__((ext_vector_type(4)));

__device__ __forceinline__ float silu_f(float v) {
    return v * (1.f / (1.f + __expf(-v)));
}
__device__ __forceinline__ float softplus_f(float v) {
    return fmaxf(v, 0.f) + log1pf(__expf(-fabsf(v)));
}

// dA[n] = exp(dtv*An[n]); fast path when An[n] == -(n+1) (true for this model:
// A_log = log(arange(1..16)) broadcast): dA[n] = p^(n+1), p = exp(-dtv).
__device__ __forceinline__ void compute_dA(float dtv, const float* An,
                                           bool structured, float* dA) {
    if (structured) {
        float p1 = __expf(-dtv);
        float p2 = p1*p1, p4 = p2*p2, p8 = p4*p4;
        dA[0]=p1;      dA[1]=p2;      dA[2]=p2*p1;    dA[3]=p4;
        dA[4]=p4*p1;   dA[5]=p4*p2;   dA[6]=p4*dA[2]; dA[7]=p8;
        dA[8]=p8*p1;   dA[9]=p8*p2;   dA[10]=p8*dA[2];dA[11]=p8*p4;
        dA[12]=p8*dA[4];dA[13]=p8*dA[5];dA[14]=p8*dA[6];dA[15]=p8*p8;
    } else {
        #pragma unroll
        for (int n = 0; n < 16; ++n) dA[n] = __expf(dtv*An[n]);
    }
}

// ---------------- prep: weight conversion + Wbig build + input proj + LN0 ----------------
// Wbig[layer][576][512] fp16: rows 0-511 = Wdt = dtw @ Wx[0:16]  (dt folded into GEMM)
//                              rows 512-543 = Wx[16:48] (B,C rows); rows 544-575 = 0
#define NIN_W  (4*1024*256)
#define NOUT_W (4*256*512)
#define NS0    (NIN_W + NOUT_W)
#define NB_S0  (NS0/256)          // 6144
#define NB_S1  (4*64*512/256)     // 512
#define NB_S2  32                 // 4 layers x 8 e-chunks
__global__ __launch_bounds__(256) void prep_kernel(
    const float* __restrict__ inw, const float* __restrict__ ow,
    const float* __restrict__ xw, const float* __restrict__ dtw,
    _Float16* __restrict__ wh_in, _Float16* __restrict__ wh_out,
    _Float16* __restrict__ Wbig,
    const float* __restrict__ obs, const float* __restrict__ ipw,
    const float* __restrict__ ipb, const float* __restrict__ nw,
    const float* __restrict__ nb, float* __restrict__ x,
    _Float16* __restrict__ xn_h) {
    __shared__ float swxT[512][16];   // S2: xw[0:16] transposed [k][r]
    __shared__ float ps[4];
    __shared__ float mean_s, rstd_s;
    int tid = threadIdx.x;
    if (blockIdx.x < NB_S0) {
        int idx = blockIdx.x*256 + tid;
        if (idx < NIN_W) wh_in[idx] = (_Float16)inw[idx];
        else wh_out[idx - NIN_W] = (_Float16)ow[idx - NIN_W];
        return;
    }
    if (blockIdx.x < NB_S0 + NB_S1) {
        int idx = (blockIdx.x - NB_S0)*256 + tid;   // 0..131071
        int L = idx >> 15;
        int rem = idx & 32767;
        int j = rem >> 9, k = rem & 511;
        float v = (j < 32) ? xw[(size_t)L*48*512 + (size_t)(16 + j)*512 + k] : 0.f;
        Wbig[(size_t)L*576*512 + (size_t)(512 + j)*512 + k] = (_Float16)v;
        return;
    }
    if (blockIdx.x < NB_S0 + NB_S1 + NB_S2) {
        int q2 = blockIdx.x - NB_S0 - NB_S1;        // 0..31
        int L = q2 >> 3, E = q2 & 7;
        const float* xwL = xw + (size_t)L*48*512;
        #pragma unroll
        for (int i = 0; i < 32; ++i) {
            int q = tid + 256*i;                    // 0..8191
            int r = q >> 9, k = q & 511;
            swxT[k][r] = xwL[(size_t)r*512 + k];
        }
        __syncthreads();
        int e = E*64 + (tid >> 2), kq = tid & 3;
        float dwr[16];
        const float* dtwp = dtw + ((size_t)L*512 + e)*16;
        #pragma unroll
        for (int r = 0; r < 16; ++r) dwr[r] = dtwp[r];
        _Float16* wb = Wbig + (size_t)L*576*512 + (size_t)e*512;
        for (int kk = 0; kk < 128; ++kk) {
            int k = kq*128 + kk;
            const float* sp = &swxT[k][0];
            float acc = 0.f;
            #pragma unroll
            for (int r = 0; r < 16; ++r) acc += dwr[r]*sp[r];
            wb[k] = (_Float16)acc;
        }
        return;
    }
    // S3: input projection + SiLU + LN(layer0)
    int t = blockIdx.x - NB_S0 - NB_S1 - NB_S2;
    __shared__ float so[OBS];
    if (tid < OBS) so[tid] = obs[t*OBS + tid];
    __syncthreads();
    float acc = ipb[tid];
    const float* wr = ipw + tid*OBS;
    #pragma unroll
    for (int k = 0; k < OBS; ++k) acc += so[k]*wr[k];
    float v = silu_f(acc);
    x[t*DM + tid] = v;
    float s = v;
    #pragma unroll
    for (int off = 32; off; off >>= 1) s += __shfl_down(s, off);
    int wid = tid >> 6, lane = tid & 63;
    if (lane == 0) ps[wid] = s;
    __syncthreads();
    if (tid == 0) mean_s = (ps[0]+ps[1]+ps[2]+ps[3]) * (1.f/DM);
    __syncthreads();
    float m = mean_s;
    float dd = v - m;
    float sq = dd*dd;
    #pragma unroll
    for (int off = 32; off; off >>= 1) sq += __shfl_down(sq, off);
    if (lane == 0) ps[wid] = sq;
    __syncthreads();
    if (tid == 0) rstd_s = rsqrtf((ps[0]+ps[1]+ps[2]+ps[3])*(1.f/DM) + 1e-5f);
    __syncthreads();
    xn_h[t*DM + tid] = (_Float16)(dd * rstd_s * nw[tid] + nb[tid]);
}

// ---------------- fp16 MFMA GEMM with fused epilogues ----------------
// EPI: 1 = fp16 C
//      2 = resid + x fp32 + LN -> xn_h (BM=64,BN=256,WM=4,WN=1)
//      3 = resid + policy/value heads -> out (same tile shape)
template<int BM, int BN, int WM, int WN, int EPI>
__global__ __launch_bounds__(256) void hgemm_nt(
    const _Float16* __restrict__ A, const _Float16* __restrict__ W,
    void* __restrict__ Cout, const float* __restrict__ resid,
    int M, int N, int K, int ldc,
    const float* __restrict__ e0, const float* __restrict__ e1,
    const float* __restrict__ e2, const float* __restrict__ e3,
    const float* __restrict__ e4,
    float* __restrict__ xout, _Float16* __restrict__ xnh) {
    constexpr int MFR = BM/(WM*16);
    constexpr int NFR = BN/(WN*16);
    __shared__ _Float16 As[BM*64];
    __shared__ _Float16 Bs[BN*64];
    int tid = threadIdx.x;
    int r0 = blockIdx.y*BM, c0 = blockIdx.x*BN;
    int w = tid >> 6, lane = tid & 63;
    int wr = w / WN, wc = w % WN;
    floatx4 acc[MFR][NFR];
    #pragma unroll
    for (int i = 0; i < MFR; ++i)
        #pragma unroll
        for (int j = 0; j < NFR; ++j)
            acc[i][j] = (floatx4)0.f;

    for (int k0 = 0; k0 < K; k0 += 64) {
        #pragma unroll
        for (int c = 0; c < BM/32; ++c) {
            int q = tid + 256*c;
            int row = q >> 3, cc = (q & 7)*8;
            half8 v = *(const half8*)&A[(size_t)(r0 + row)*K + k0 + cc];
            *(half8*)&As[row*64 + (cc ^ ((row & 7) << 3))] = v;
        }
        #pragma unroll
        for (int c = 0; c < BN/32; ++c) {
            int q = tid + 256*c;
            int row = q >> 3, cc = (q & 7)*8;
            half8 v = *(const half8*)&W[(size_t)(c0 + row)*K + k0 + cc];
            *(half8*)&Bs[row*64 + (cc ^ ((row & 7) << 3))] = v;
        }
        __syncthreads();
        #pragma unroll
        for (int kc = 0; kc < 2; ++kc) {
            half8 a[MFR], b[NFR];
            int col = kc*32 + (lane >> 4)*8;
            #pragma unroll
            for (int i = 0; i < MFR; ++i) {
                int row = wr*(BM/WM) + i*16 + (lane & 15);
                a[i] = *(const half8*)&As[row*64 + (col ^ ((row & 7) << 3))];
            }
            #pragma unroll
            for (int j = 0; j < NFR; ++j) {
                int row = wc*(BN/WN) + j*16 + (lane & 15);
                b[j] = *(const half8*)&Bs[row*64 + (col ^ ((row & 7) << 3))];
            }
            #pragma unroll
            for (int i = 0; i < MFR; ++i)
                #pragma unroll
                for (int j = 0; j < NFR; ++j)
                    acc[i][j] = __builtin_amdgcn_mfma_f32_16x16x32_f16(a[i], b[j], acc[i][j], 0, 0, 0);
        }
        __syncthreads();
    }
    // C/D mapping: col = lane&15, row = (lane>>4)*4 + reg
    if constexpr (EPI == 1) {
        _Float16* C = (_Float16*)Cout;
        #pragma unroll
        for (int i = 0; i < MFR; ++i) {
            int m0 = r0 + wr*(BM/WM) + i*16 + (lane >> 4)*4;
            #pragma unroll
            for (int j = 0; j < NFR; ++j) {
                int col = c0 + wc*(BN/WN) + j*16 + (lane & 15);
                #pragma unroll
                for (int t = 0; t < 4; ++t)
                    C[(size_t)(m0 + t)*ldc + col] = (_Float16)acc[i][j][t];
            }
        }
    } else if constexpr (EPI == 2 || EPI == 3) {
        int g = lane >> 4, ln16 = lane & 15;
        #pragma unroll
        for (int t = 0; t < 4; ++t) {
            int row = r0 + wr*16 + g*4 + t;
            #pragma unroll
            for (int j = 0; j < NFR; ++j)
                acc[0][j][t] += resid[(size_t)row*DM + j*16 + ln16];
        }
        if constexpr (EPI == 2) {
            #pragma unroll
            for (int t = 0; t < 4; ++t) {
                int row = r0 + wr*16 + g*4 + t;
                float s = 0.f, sq = 0.f;
                #pragma unroll
                for (int j = 0; j < NFR; ++j) {
                    float v = acc[0][j][t];
                    xout[(size_t)row*DM + j*16 + ln16] = v;
                    s += v; sq += v*v;
                }
                #pragma unroll
                for (int msk = 1; msk < 16; msk <<= 1) {
                    s += __shfl_xor(s, msk);
                    sq += __shfl_xor(sq, msk);
                }
                float mean = s * (1.f/DM);
                float rstd = rsqrtf(sq*(1.f/DM) - mean*mean + 1e-5f);
                #pragma unroll
                for (int j = 0; j < NFR; ++j) {
                    int col = j*16 + ln16;
                    float v = acc[0][j][t];
                    xnh[(size_t)row*DM + col] =
                        (_Float16)((v - mean)*rstd*e0[col] + e1[col]);
                }
            }
        } else {
            float* out = xout;
            #pragma unroll
            for (int t = 0; t < 4; ++t) {
                int row = r0 + wr*16 + g*4 + t;
                float m0 = 0.f, m1 = 0.f, vv = 0.f;
                #pragma unroll
                for (int j = 0; j < NFR; ++j) {
                    int col = j*16 + ln16;
                    float v = acc[0][j][t];
                    m0 += v*e0[col]; m1 += v*e0[DM + col]; vv += v*e3[col];
                }
                #pragma unroll
                for (int msk = 1; msk < 16; msk <<= 1) {
                    m0 += __shfl_xor(m0, msk);
                    m1 += __shfl_xor(m1, msk);
                    vv += __shfl_xor(vv, msk);
                }
                if (ln16 == 0) {
                    out[row*2 + 0] = m0 + e1[0];
                    out[row*2 + 1] = m1 + e1[1];
                    out[2*NTOK + row*2 + 0] = __expf(e2[0]);
                    out[2*NTOK + row*2 + 1] = __expf(e2[1]);
                    out[4*NTOK + row] = vv + e4[0];
                }
            }
        }
    }
}

// ---------------- causal depthwise conv (width 4) + SiLU -> fp16 ----------------
__global__ __launch_bounds__(256) void conv_silu_kernel(
    const _Float16* __restrict__ xz_h, const float* __restrict__ cw,
    const float* __restrict__ cb, _Float16* __restrict__ xi_h) {
    int idx = blockIdx.x*blockDim.x + threadIdx.x;
    if (idx >= NTOK*DI) return;
    int d = idx & (DI-1); int t = idx >> 9;
    int l = t & (Lseq-1);
    float acc = cb[d];
    #pragma unroll
    for (int k = 0; k < 4; ++k) {
        int ls = l - 3 + k;
        if (ls >= 0) acc += (float)xz_h[(size_t)(t-3+k)*1024 + d] * cw[d*4 + k];
    }
    xi_h[idx] = (_Float16)silu_f(acc);
}

// ---------------- big GEMM: dt (folded) + B/C ----------------
// N=576: cols 0-511 -> dt_h = softplus(xi@Wdt^T + dtb), fp16
//        cols 512-543 -> dbc32 (B,C) fp32
__global__ __launch_bounds__(256) void big_gemm(
    const _Float16* __restrict__ xi_h, const _Float16* __restrict__ Wb,
    const float* __restrict__ dtb, _Float16* __restrict__ dt_h,
    float* __restrict__ dbc32) {
    __shared__ _Float16 As[32*64];
    __shared__ _Float16 Bs[64*64];
    int tid = threadIdx.x;
    int r0 = blockIdx.y*32, c0 = blockIdx.x*64;
    int w = tid >> 6, lane = tid & 63;
    int wr = w >> 1, wc = w & 1;
    floatx4 acc[2];
    acc[0] = (floatx4)0.f; acc[1] = (floatx4)0.f;
    for (int k0 = 0; k0 < 512; k0 += 64) {
        {
            int row = tid >> 3, cc = (tid & 7)*8;
            half8 v = *(const half8*)&xi_h[(size_t)(r0 + row)*512 + k0 + cc];
            *(half8*)&As[row*64 + (cc ^ ((row & 7) << 3))] = v;
        }
        #pragma unroll
        for (int c = 0; c < 2; ++c) {
            int q = tid + 256*c;
            int row = q >> 3, cc = (q & 7)*8;
            half8 v = *(const half8*)&Wb[(size_t)(c0 + row)*512 + k0 + cc];
            *(half8*)&Bs[row*64 + (cc ^ ((row & 7) << 3))] = v;
        }
        __syncthreads();
        #pragma unroll
        for (int kc = 0; kc < 2; ++kc) {
            int col = kc*32 + (lane >> 4)*8;
            int arow = wr*16 + (lane & 15);
            half8 a = *(const half8*)&As[arow*64 + (col ^ ((arow & 7) << 3))];
            #pragma unroll
            for (int j = 0; j < 2; ++j) {
                int brow = wc*32 + j*16 + (lane & 15);
                half8 b = *(const half8*)&Bs[brow*64 + (col ^ ((brow & 7) << 3))];
                acc[j] = __builtin_amdgcn_mfma_f32_16x16x32_f16(a, b, acc[j], 0, 0, 0);
            }
        }
        __syncthreads();
    }
    int m0 = r0 + wr*16 + (lane >> 4)*4;
    int bx = blockIdx.x;
    #pragma unroll
    for (int j = 0; j < 2; ++j) {
        int lc = wc*32 + j*16 + (lane & 15);
        if (bx < 8) {
            int col = c0 + lc;
            float bias = dtb[col];
            #pragma unroll
            for (int t = 0; t < 4; ++t)
                dt_h[(size_t)(m0 + t)*512 + col] = (_Float16)softplus_f(acc[j][t] + bias);
        } else if (lc < 32) {
            #pragma unroll
            for (int t = 0; t < 4; ++t)
                dbc32[(size_t)(m0 + t)*32 + lc] = acc[j][t];
        }
    }
}

// ---------------- selective scan, 3-phase chunked (lean) ----------------
__global__ __launch_bounds__(256) void scan_phaseA(
    const _Float16* __restrict__ xi_h, const _Float16* __restrict__ dt_h,
    const float* __restrict__ dbc32, const float* __restrict__ a_log,
    _Float16* __restrict__ Ap, _Float16* __restrict__ He) {
    __shared__ __align__(16) float sdbc[CH*32];
    int blk = blockIdx.x;               // b*(2*NCH) + c*2 + half
    int b = blk >> 7; int rem = blk & 127; int c = rem >> 1; int half = rem & 1;
    int d = half*256 + threadIdx.x;
    {
        const float* src = dbc32 + ((size_t)(b*Lseq + c*CH))*32;
        int q = threadIdx.x;
        sdbc[q] = src[q];
        sdbc[q + 256] = src[q + 256];
    }
    float An[16];
    bool structured = true;
    #pragma unroll
    for (int n = 0; n < 16; ++n) {
        An[n] = -__expf(a_log[d*16 + n]);
        structured = structured && (fabsf(An[n] + (float)(n+1)) < 1e-4f*(n+1));
    }
    int t0 = b*Lseq + c*CH;
    float xiv[CH], dtv[CH];
    #pragma unroll
    for (int s = 0; s < CH; ++s) {
        xiv[s] = (float)xi_h[(size_t)(t0+s)*DI + d];
        dtv[s] = (float)dt_h[(size_t)(t0+s)*DI + d];
    }
    __syncthreads();
    float h[16] = {};
    float ap[16];
    #pragma unroll
    for (int n = 0; n < 16; ++n) ap[n] = 1.f;
    #pragma unroll
    for (int s = 0; s < CH; ++s) {
        float u = dtv[s]*xiv[s];
        float dA[16];
        compute_dA(dtv[s], An, structured, dA);
        float Bv[16];
        *(float4*)&Bv[0]  = *(const float4*)&sdbc[s*32 + 0];
        *(float4*)&Bv[4]  = *(const float4*)&sdbc[s*32 + 4];
        *(float4*)&Bv[8]  = *(const float4*)&sdbc[s*32 + 8];
        *(float4*)&Bv[12] = *(const float4*)&sdbc[s*32 + 12];
        #pragma unroll
        for (int n = 0; n < 16; ++n) {
            h[n] = dA[n]*h[n] + u*Bv[n];
            ap[n] *= dA[n];
        }
    }
    size_t base = ((size_t)(b*NCH + c)*16)*DI + d;
    #pragma unroll
    for (int n = 0; n < 16; ++n) {
        Ap[base + n*DI] = (_Float16)ap[n];
        He[base + n*DI] = (_Float16)h[n];
    }
}

// NOTE: h0 aliases Ap (read before write per index)
__global__ __launch_bounds__(256) void scan_phaseB(
    const _Float16* __restrict__ Ap, const _Float16* __restrict__ He,
    _Float16* __restrict__ h0) {
    int g = blockIdx.x*blockDim.x + threadIdx.x;  // 32768 threads
    int b = g >> 13; int n = (g >> 9) & 15; int d = g & 511;
    float run = 0.f;
    for (int c = 0; c < NCH; ++c) {
        size_t idx = ((size_t)(b*NCH + c)*16 + n)*DI + d;
        float a = (float)Ap[idx], e = (float)He[idx];
        h0[idx] = (_Float16)run;
        run = a*run + e;
    }
}

__global__ __launch_bounds__(256) void scan_phaseC(
    const _Float16* __restrict__ xi_h, const _Float16* __restrict__ dt_h,
    const float* __restrict__ dbc32, const float* __restrict__ a_log,
    const float* __restrict__ dskip, const _Float16* __restrict__ xz_h,
    const _Float16* __restrict__ h0, _Float16* __restrict__ yg_h) {
    __shared__ __align__(16) float sdbc[CH*32];
    int blk = blockIdx.x;
    int b = blk >> 7; int rem = blk & 127; int c = rem >> 1; int half = rem & 1;
    int d = half*256 + threadIdx.x;
    {
        const float* src = dbc32 + ((size_t)(b*Lseq + c*CH))*32;
        int q = threadIdx.x;
        sdbc[q] = src[q];
        sdbc[q + 256] = src[q + 256];
    }
    float An[16];
    bool structured = true;
    #pragma unroll
    for (int n = 0; n < 16; ++n) {
        An[n] = -__expf(a_log[d*16 + n]);
        structured = structured && (fabsf(An[n] + (float)(n+1)) < 1e-4f*(n+1));
    }
    int t0 = b*Lseq + c*CH;
    float xiv[CH], dtv[CH], zv[CH];
    #pragma unroll
    for (int s = 0; s < CH; ++s) {
        xiv[s] = (float)xi_h[(size_t)(t0+s)*DI + d];
        dtv[s] = (float)dt_h[(size_t)(t0+s)*DI + d];
        zv[s]  = (float)xz_h[(size_t)(t0+s)*1024 + DI + d];
    }
    __syncthreads();
    float h[16];
    size_t base = ((size_t)(b*NCH + c)*16)*DI + d;
    #pragma unroll
    for (int n = 0; n < 16; ++n) h[n] = (float)h0[base + n*DI];
    float ds = dskip[d];
    #pragma unroll
    for (int s = 0; s < CH; ++s) {
        float u = dtv[s]*xiv[s];
        float dA[16];
        compute_dA(dtv[s], An, structured, dA);
        float Bv[16], Cv[16];
        *(float4*)&Bv[0]  = *(const float4*)&sdbc[s*32 + 0];
        *(float4*)&Bv[4]  = *(const float4*)&sdbc[s*32 + 4];
        *(float4*)&Bv[8]  = *(const float4*)&sdbc[s*32 + 8];
        *(float4*)&Bv[12] = *(const float4*)&sdbc[s*32 + 12];
        *(float4*)&Cv[0]  = *(const float4*)&sdbc[s*32 + 16];
        *(float4*)&Cv[4]  = *(const float4*)&sdbc[s*32 + 20];
        *(float4*)&Cv[8]  = *(const float4*)&sdbc[s*32 + 24];
        *(float4*)&Cv[12] = *(const float4*)&sdbc[s*32 + 28];
        float y = ds*xiv[s];
        #pragma unroll
        for (int n = 0; n < 16; ++n) {
            h[n] = dA[n]*h[n] + u*Bv[n];
            y += h[n]*Cv[n];
        }
        yg_h[(size_t)(t0+s)*DI + d] = (_Float16)(y * silu_f(zv[s]));
    }
}

extern "C" void kernel_launch(void* const* d_in, const int* in_sizes, int n_in,
                              void* d_out, int out_size, void* d_ws, size_t ws_size,
                              hipStream_t stream) {
    const float* obs = (const float*)d_in[0];
    const float* ipw = (const float*)d_in[1];
    const float* ipb = (const float*)d_in[2];
    const float* nw  = (const float*)d_in[3];
    const float* nb  = (const float*)d_in[4];
    const float* inw = (const float*)d_in[5];
    const float* cw  = (const float*)d_in[6];
    const float* cb  = (const float*)d_in[7];
    const float* xw  = (const float*)d_in[8];
    const float* dtw = (const float*)d_in[9];
    const float* dtb = (const float*)d_in[10];
    const float* alog= (const float*)d_in[11];
    const float* dsk = (const float*)d_in[12];
    const float* ow  = (const float*)d_in[13];
    const float* pw  = (const float*)d_in[14];
    const float* pb  = (const float*)d_in[15];
    const float* ls  = (const float*)d_in[16];
    const float* vw  = (const float*)d_in[17];
    const float* vb  = (const float*)d_in[18];
    float* out = (float*)d_out;

    float* ws = (float*)d_ws;
    float* x     = ws;                  // 1,048,576 f32
    float* dbc32 = x + 1048576;         //   131,072 f32
    _Float16* f16b  = (_Float16*)(dbc32 + 131072);
    _Float16* xz_h  = f16b;                   // 4,194,304
    _Float16* xn_h  = xz_h  + 4194304;        // 1,048,576
    _Float16* xi_h  = xn_h  + 1048576;        // 2,097,152
    _Float16* dt_h  = xi_h  + 2097152;        // 2,097,152
    _Float16* yg_h  = dt_h  + 2097152;        // 2,097,152
    _Float16* Ap_h  = yg_h  + 2097152;        // 2,097,152 (h0 aliases Ap)
    _Float16* He_h  = Ap_h  + 2097152;        // 2,097,152
    _Float16* h0_h  = Ap_h;                   // alias (phaseB reads before write)
    _Float16* wh_in = He_h  + 2097152;        // 1,048,576
    _Float16* wh_out= wh_in + 1048576;        //   524,288
    _Float16* Wbig  = wh_out+ 524288;         // 1,179,648

    prep_kernel<<<NB_S0 + NB_S1 + NB_S2 + NTOK, 256, 0, stream>>>(
        inw, ow, xw, dtw, wh_in, wh_out, Wbig,
        obs, ipw, ipb, nw, nb, x, xn_h);

    for (int i = 0; i < 4; ++i) {
        {   // in_proj: M=4096, N=1024, K=256 -> xz fp16
            dim3 g(1024/64, NTOK/128);
            hgemm_nt<128,64,2,2,1><<<g, 256, 0, stream>>>(
                xn_h, wh_in + (size_t)i*1024*256, xz_h, nullptr, NTOK, 1024, 256, 1024,
                nullptr, nullptr, nullptr, nullptr, nullptr, nullptr, nullptr);
        }
        conv_silu_kernel<<<(NTOK*DI)/256, 256, 0, stream>>>(
            xz_h, cw + (size_t)i*DI*4, cb + i*DI, xi_h);
        {   // big GEMM: dt (512 cols) + B/C (32 cols)
            dim3 g(9, NTOK/32);
            big_gemm<<<g, 256, 0, stream>>>(
                xi_h, Wbig + (size_t)i*576*512, dtb + i*DI, dt_h, dbc32);
        }
        scan_phaseA<<<Bsz*NCH*2, 256, 0, stream>>>(
            xi_h, dt_h, dbc32, alog + (size_t)i*DI*DST, Ap_h, He_h);
        scan_phaseB<<<128, 256, 0, stream>>>(Ap_h, He_h, h0_h);
        scan_phaseC<<<Bsz*NCH*2, 256, 0, stream>>>(
            xi_h, dt_h, dbc32, alog + (size_t)i*DI*DST,
            dsk + i*DI, xz_h, h0_h, yg_h);
        {   // out_proj: M=4096, N=256, K=512 + resid; fused LN / heads
            dim3 g(1, NTOK/64);
            if (i < 3) {
                hgemm_nt<64,256,4,1,2><<<g, 256, 0, stream>>>(
                    yg_h, wh_out + (size_t)i*256*512, nullptr, x, NTOK, 256, 512, 256,
                    nw + (i+1)*DM, nb + (i+1)*DM, nullptr, nullptr, nullptr, x, xn_h);
            } else {
                hgemm_nt<64,256,4,1,3><<<g, 256, 0, stream>>>(
                    yg_h, wh_out + (size_t)i*256*512, nullptr, x, NTOK, 256, 512, 256,
                    pw, pb, ls, vw, vb, out, nullptr);
            }
        }
    }
}